// Round 4
// baseline (331.427 us; speedup 1.0000x reference)
//
#include <hip/hip_runtime.h>

// PrecRec: confusion-matrix counts over 10 sigmoid thresholds.
//
// R10: deeper MLP at constant occupancy.
// Ladder: R6 130 us (3.1 TB/s) -> R7 nt loads 83 us (4.85 TB/s) -> R9
// 2-deep x 12-load register double-buffer ~75 us (~5.4 TB/s; count_kernel
// fell below the harness's 512MiB re-poison fills at ~77-79 us, so exact
// counters unavailable; dur_us decomposition 330 = count + ~255 fill).
// Harness fills prove this machine sustains 6.9 TB/s one-directional ->
// read-side headroom still exists; R9's +10% from 3->12 in-flight loads
// says latency-limited, not service-walled.
// R10: 4-deep x 6-load rotation (batch = 128 groups: p0,p1,m0,m1,t0,t1).
// Same 96 payload VGPRs as R9 but ~18 loads in flight (3 batches ahead),
// smoother issue cadence (consume phase ~208 cyc vs ~420). Grid unchanged
// 1024x256 (16 waves/CU at VGPR<=128); 16 iters/wave, exactly divisible.
// Gates: WRITE ~1.4 MB, FETCH ~201 MB, VGPR 110-128.
// Predict: MLP-bound -> count 63-70, dur_us 318-325; wall -> dur_us ~330
// and ~5.4 TB/s mixed read is the ceiling (declare roofline, keep R9/R10).
//
// Bucketing math unchanged since R5 (absmax 0.0 verified): packed u64
// histograms, level-1 5-bit x 11 (cap 31 >= 8 elems/batch), level-2
// 10-bit x 11 (cap 1023 >= 128 elems/thread), suffix sums in finalize.

#define NTHR 10
#define NBKT 11            // bucket = #thresholds passed, 0..10
#define NCNT 22            // ws: [0..10]=P-bucket counts, [11..21]=TP-bucket
#define WS_STRIDE 16       // 64 B between counters

typedef unsigned long long u64;
typedef unsigned u32;
typedef float __attribute__((ext_vector_type(4))) f32x4;
typedef int   __attribute__((ext_vector_type(4))) i32x4;

__device__ __forceinline__ unsigned wave_reduce_add(unsigned v) {
#pragma unroll
    for (int off = 32; off > 0; off >>= 1)
        v += __shfl_down(v, off, 64);
    return v;
}

__global__ __launch_bounds__(64) void zero_ws_kernel(u32* __restrict__ ws) {
    int i = threadIdx.x;
    if (i < NCNT) ws[i * WS_STRIDE] = 0u;
}

__device__ __forceinline__ void acc_elem(float x, u32 mm, u32 tt, u64& hP, u64& hT) {
    u32 mt = mm & tt;
    // bucket = #(sigmoid(x) > j/11) = min(10, floor(11*sigmoid(x)))
    float e = __expf(-x);                          // v_mul + v_exp
    float s = __builtin_amdgcn_rcpf(1.0f + e);     // v_add + v_rcp
    int bi = (int)(s * 11.0f);                     // v_mul + v_cvt (s>=0)
    u32 b = (u32)(bi > 10 ? 10 : bi);              // guard s==1.0
    u32 sh = b * 5u;
    hP += (u64)mm << sh;
    hT += (u64)mt << sh;
}

__device__ __forceinline__ void acc_vec(const f32x4& p, const i32x4& m, const i32x4& t,
                                        u64& hP, u64& hT) {
    acc_elem(p.x, (u32)m.x, (u32)t.x, hP, hT);
    acc_elem(p.y, (u32)m.y, (u32)t.y, hP, hT);
    acc_elem(p.z, (u32)m.z, (u32)t.z, hP, hT);
    acc_elem(p.w, (u32)m.w, (u32)t.w, hP, hT);
}

__device__ __forceinline__ void flush_hist(u64& hP, u64& hT,
                                           u64& Plo, u64& Phi, u64& Tlo, u64& Thi) {
#pragma unroll
    for (int b = 0; b < 6; ++b) {
        Plo += (u64)((u32)(hP >> (5 * b)) & 31u) << (10 * b);
        Tlo += (u64)((u32)(hT >> (5 * b)) & 31u) << (10 * b);
    }
#pragma unroll
    for (int b = 6; b < NBKT; ++b) {
        Phi += (u64)((u32)(hP >> (5 * b)) & 31u) << (10 * (b - 6));
        Thi += (u64)((u32)(hT >> (5 * b)) & 31u) << (10 * (b - 6));
    }
    hP = 0ull; hT = 0ull;
}

__device__ __forceinline__ f32x4 zf4() { f32x4 v; v.x = v.y = v.z = v.w = 0.0f; return v; }
__device__ __forceinline__ i32x4 zi4() { i32x4 v; v.x = v.y = v.z = v.w = 0;    return v; }

#define NTL(p) __builtin_nontemporal_load(p)

// Load one 128-group batch into named register set S: 6 x 16B nt loads
// (2 pred, 2 mask, 2 targ), all independent. Guard never triggers at the
// bench size (exactly divisible) but keeps the kernel general.
#define LOAD_BATCH(S, b)                                                      \
    do {                                                                      \
        if ((b) + 128 <= nvec) {                                              \
            S##p0 = NTL(pred4 + (b) +      lane);                             \
            S##p1 = NTL(pred4 + (b) + 64 + lane);                             \
            S##m0 = NTL(mask4 + (b) +      lane);                             \
            S##m1 = NTL(mask4 + (b) + 64 + lane);                             \
            S##t0 = NTL(targ4 + (b) +      lane);                             \
            S##t1 = NTL(targ4 + (b) + 64 + lane);                             \
        } else {                                                              \
            int g0 = (b) +      lane;                                         \
            int g1 = (b) + 64 + lane;                                         \
            if (g0 < nvec) { S##p0 = NTL(pred4 + g0); S##m0 = NTL(mask4 + g0);\
                             S##t0 = NTL(targ4 + g0); }                       \
            else           { S##p0 = zf4(); S##m0 = zi4(); S##t0 = zi4(); }   \
            if (g1 < nvec) { S##p1 = NTL(pred4 + g1); S##m1 = NTL(mask4 + g1);\
                             S##t1 = NTL(targ4 + g1); }                       \
            else           { S##p1 = zf4(); S##m1 = zi4(); S##t1 = zi4(); }   \
        }                                                                     \
    } while (0)

#define CONSUME_BATCH(S)                                                      \
    do {                                                                      \
        u64 hP = 0ull, hT = 0ull;                                             \
        acc_vec(S##p0, S##m0, S##t0, hP, hT);                                 \
        acc_vec(S##p1, S##m1, S##t1, hP, hT);                                 \
        flush_hist(hP, hT, Plo, Phi, Tlo, Thi);                               \
    } while (0)

__global__ __launch_bounds__(256) void count_kernel(
        const f32x4* __restrict__ pred4,
        const i32x4* __restrict__ mask4,
        const i32x4* __restrict__ targ4,
        const float* __restrict__ pred,
        const int*   __restrict__ mask,
        const int*   __restrict__ targ,
        u32* __restrict__ ws, int nvec, int n) {
    u64 Plo = 0ull, Phi = 0ull, Tlo = 0ull, Thi = 0ull;

    const int tid    = blockIdx.x * blockDim.x + threadIdx.x;
    const int lane   = tid & 63;
    const int waveId = tid >> 6;
    const int totalWaves = (gridDim.x * blockDim.x) >> 6;
    const int strideB    = totalWaves << 7;     // waves * 128 groups/batch

    // 4-deep register pipeline over named sets A,B,C,D: while batch h is
    // consumed, batches h+s, h+2s are resident and h+3s is being loaded ->
    // ~18 nt loads in flight per wave continuously.
    {
        f32x4 Ap0, Ap1, Bp0, Bp1, Cp0, Cp1, Dp0, Dp1;
        i32x4 Am0, Am1, Bm0, Bm1, Cm0, Cm1, Dm0, Dm1;
        i32x4 At0, At1, Bt0, Bt1, Ct0, Ct1, Dt0, Dt1;

        int h = waveId << 7;                    // head: next batch to consume
        if (h < nvec) {
            LOAD_BATCH(A, h);
            if (h + strideB < nvec)     LOAD_BATCH(B, h + strideB);
            if (h + 2 * strideB < nvec) LOAD_BATCH(C, h + 2 * strideB);
            for (;;) {
                int nb = h + 3 * strideB;
                if (nb < nvec) LOAD_BATCH(D, nb);
                CONSUME_BATCH(A);
                h += strideB;
                if (h >= nvec) break;

                nb = h + 3 * strideB;
                if (nb < nvec) LOAD_BATCH(A, nb);
                CONSUME_BATCH(B);
                h += strideB;
                if (h >= nvec) break;

                nb = h + 3 * strideB;
                if (nb < nvec) LOAD_BATCH(B, nb);
                CONSUME_BATCH(C);
                h += strideB;
                if (h >= nvec) break;

                nb = h + 3 * strideB;
                if (nb < nvec) LOAD_BATCH(C, nb);
                CONSUME_BATCH(D);
                h += strideB;
                if (h >= nvec) break;
            }
        }
    }

    // scalar tail (n % 4; empty at bench size)
    {
        int i = nvec * 4 + tid;
        if (i < n) {
            u64 hP = 0ull, hT = 0ull;
            acc_elem(pred[i], (u32)mask[i], (u32)targ[i], hP, hT);
            flush_hist(hP, hT, Plo, Phi, Tlo, Thi);
        }
    }

    // unpack level-2 (10-bit fields; per-thread elems = 128 << 1023 cap)
    u32 vals[NCNT];
#pragma unroll
    for (int b = 0; b < 6; ++b) {
        vals[b]        = (u32)(Plo >> (10 * b)) & 1023u;
        vals[NBKT + b] = (u32)(Tlo >> (10 * b)) & 1023u;
    }
#pragma unroll
    for (int b = 6; b < NBKT; ++b) {
        vals[b]        = (u32)(Phi >> (10 * (b - 6))) & 1023u;
        vals[NBKT + b] = (u32)(Thi >> (10 * (b - 6))) & 1023u;
    }
#pragma unroll
    for (int c = 0; c < NCNT; ++c) vals[c] = wave_reduce_add(vals[c]);

    __shared__ u32 partial[4][NCNT];
    const int wave = threadIdx.x >> 6;
    if ((threadIdx.x & 63) == 0) {
#pragma unroll
        for (int c = 0; c < NCNT; ++c) partial[wave][c] = vals[c];
    }
    __syncthreads();
    if (threadIdx.x < NCNT) {
        u32 s = partial[0][threadIdx.x] + partial[1][threadIdx.x] +
                partial[2][threadIdx.x] + partial[3][threadIdx.x];
        atomicAdd(&ws[threadIdx.x * WS_STRIDE], s);
    }
}

__global__ __launch_bounds__(64) void finalize_kernel(const u32* __restrict__ ws,
                                                      float* __restrict__ out) {
    int j = threadIdx.x;
    if (j < NTHR) {
        u32 totM = 0u, totT = 0u, p = 0u, tp = 0u;
#pragma unroll
        for (int b = 0; b < NBKT; ++b) {
            u32 vP = ws[b * WS_STRIDE];
            u32 vT = ws[(NBKT + b) * WS_STRIDE];
            totM += vP; totT += vT;
            if (b > j) { p += vP; tp += vT; }
        }
        u32 fp = p - tp;
        u32 fn = totT - tp;
        u32 tn = totM - p - fn;
        out[j]            = (float)tp;
        out[NTHR + j]     = (float)fp;
        out[2 * NTHR + j] = (float)tn;
        out[3 * NTHR + j] = (float)fn;
    }
}

extern "C" void kernel_launch(void* const* d_in, const int* in_sizes, int n_in,
                              void* d_out, int out_size, void* d_ws, size_t ws_size,
                              hipStream_t stream) {
    const float* pred = (const float*)d_in[0];
    const int*   mask = (const int*)d_in[1];
    const int*   targ = (const int*)d_in[2];
    u32*         ws   = (u32*)d_ws;
    float*       out  = (float*)d_out;

    const int n    = in_sizes[0];
    const int nvec = n / 4;

    zero_ws_kernel<<<1, 64, 0, stream>>>(ws);

    // 1024 blocks x 256 = 4096 waves (16/CU at VGPR<=128); 16 batches/wave
    // at the bench size, 13+ fully covered by the 4-deep pipeline.
    const int blocks = 1024;
    count_kernel<<<blocks, 256, 0, stream>>>(
        (const f32x4*)pred, (const i32x4*)mask, (const i32x4*)targ,
        pred, mask, targ, ws, nvec, n);

    finalize_kernel<<<1, 64, 0, stream>>>(ws, out);
}